// Round 14
// baseline (653.142 us; speedup 1.0000x reference)
//
#include <hip/hip_runtime.h>

#define NN 100000
#define LN_EPS 1e-5f
#define BSH 6                       // 64 nodes per bucket
#define BNODES 64
#define NBK ((NN + 63) >> 6)        // 1563 buckets
#define EC 6144                     // edges per partition chunk

typedef unsigned int uint_t;
typedef unsigned short ushort_t;
typedef __attribute__((ext_vector_type(8))) short short8v;
typedef __attribute__((ext_vector_type(4))) float f32x4;

// ---- bf16 helpers ----
// Manual RNE pack ONLY (HW cvt_pk rounds differently: r8; dot2 truncates: r9).
// k_agg loop SHAPE is load-bearing (r12) — do not restructure the agg loops.

__device__ __forceinline__ uint_t cvtpk(float a, float b) {
  uint_t ua = __float_as_uint(a);
  ua = (ua + 0x7FFFu + ((ua >> 16) & 1u)) >> 16;
  uint_t ub = __float_as_uint(b);
  ub = (ub + 0x7FFFu + ((ub >> 16) & 1u)) & 0xFFFF0000u;
  return ua | ub;
}
__device__ __forceinline__ ushort_t bf16_1(float x) {
  uint_t u = __float_as_uint(x);
  return (ushort_t)((u + 0x7FFFu + ((u >> 16) & 1u)) >> 16);
}
__device__ __forceinline__ float bf_lo(uint_t u) { return __uint_as_float(u << 16); }
__device__ __forceinline__ float bf_hi(uint_t u) { return __uint_as_float(u & 0xFFFF0000u); }

// ---------------- scan over gmat matrices (both graphs via blockIdx.y) ------

__global__ __launch_bounds__(256) void k_scanA32(const int* in0, const int* in1,
                                                 int* out0, int* out1,
                                                 int* bsum0, int* bsum1, int n) {
  const int* in = blockIdx.y ? in1 : in0;
  int* out = blockIdx.y ? out1 : out0;
  int* bsum = blockIdx.y ? bsum1 : bsum0;
  __shared__ int sh[256];
  int t = threadIdx.x;
  int base = blockIdx.x * 8192 + t * 32;
  int v[32];
  int s = 0;
#pragma unroll
  for (int i = 0; i < 32; ++i) {
    int idx = base + i;
    v[i] = (idx < n) ? in[idx] : 0;
    s += v[i];
  }
  sh[t] = s;
  __syncthreads();
  for (int d = 1; d < 256; d <<= 1) {
    int a = (t >= d) ? sh[t - d] : 0;
    __syncthreads();
    sh[t] += a;
    __syncthreads();
  }
  int run = sh[t] - s;
  if (t == 255) bsum[blockIdx.x] = sh[255];
#pragma unroll
  for (int i = 0; i < 32; ++i) {
    int idx = base + i;
    if (idx < n) out[idx] = run;
    run += v[i];
  }
}

__global__ void k_scanB(int* bsum0, int* bsum1, int nb) {
  int* bsum = blockIdx.y ? bsum1 : bsum0;
  int t = threadIdx.x;
  int x = (t < nb) ? bsum[t] : 0;
  int incl = x;
#pragma unroll
  for (int d = 1; d < 64; d <<= 1) {
    int y = __shfl_up(incl, d, 64);
    if (t >= d) incl += y;
  }
  if (t < nb) bsum[t] = incl - x;
}

__global__ void k_scanC32(int* rp0, int* rp1, const int* bsum0, const int* bsum1,
                          int n, int total) {
  int* rp = blockIdx.y ? rp1 : rp0;
  const int* bsum = blockIdx.y ? bsum1 : bsum0;
  int i = blockIdx.x * 256 + threadIdx.x;
  if (i < n) rp[i] += bsum[i >> 13];
  else if (i == n) rp[n] = total;
}

// ---------------- partition: per-chunk histogram over buckets (both graphs) --

__global__ __launch_bounds__(256) void k_phist(const int* dst0, const int* dst1,
                                               int* gmatC0, int* gmatC1, int E, int B) {
  const int* dst = blockIdx.y ? dst1 : dst0;
  int* gmatC = blockIdx.y ? gmatC1 : gmatC0;
  __shared__ int lh[NBK];
  int t = threadIdx.x;
  for (int i = t; i < NBK; i += 256) lh[i] = 0;
  __syncthreads();
  int base = blockIdx.x * EC;
  int end = min(E, base + EC);
  for (int i = base + t; i < end; i += 256) atomicAdd(&lh[dst[i] >> BSH], 1);
  __syncthreads();
  for (int b = t; b < NBK; b += 256) gmatC[(size_t)b * B + blockIdx.x] = lh[b];
}

// LDS counting sort of one chunk; flat copy-out via binary search (both graphs).
// dst chunk register-cached (read global once). parts[pos] = (dst&63)<<20 | src
__global__ __launch_bounds__(256) void k_pscatter(const int* src0, const int* src1,
                                                  const int* dst0, const int* dst1,
                                                  const int* gmatS0, const int* gmatS1,
                                                  uint_t* parts0, uint_t* parts1,
                                                  int E, int B) {
  const int* src = blockIdx.y ? src1 : src0;
  const int* dst = blockIdx.y ? dst1 : dst0;
  const int* gmatS = blockIdx.y ? gmatS1 : gmatS0;
  uint_t* parts = blockIdx.y ? parts1 : parts0;
  __shared__ uint_t stage[EC];   // 24 KB
  __shared__ int lh[2048];
  __shared__ int lcur[NBK];
  __shared__ int sh[256];
  int t = threadIdx.x;
  int c = blockIdx.x;
  for (int i = t; i < 2048; i += 256) lh[i] = 0;
  __syncthreads();
  int base = c * EC;
  int end = min(E, base + EC);
  int cnt = end - base;
  int dreg[EC / 256];           // 24 dst values per thread
  int nIt = 0;
  for (int i = base + t; i < end; i += 256) {
    int d = dst[i];
    dreg[nIt++] = d;
    atomicAdd(&lh[d >> BSH], 1);
  }
  __syncthreads();
  int loc[8];
  int s = 0;
#pragma unroll
  for (int i = 0; i < 8; ++i) {
    loc[i] = lh[t * 8 + i];
    s += loc[i];
  }
  sh[t] = s;
  __syncthreads();
  for (int d = 1; d < 256; d <<= 1) {
    int a = (t >= d) ? sh[t - d] : 0;
    __syncthreads();
    sh[t] += a;
    __syncthreads();
  }
  int run = sh[t] - s;
#pragma unroll
  for (int i = 0; i < 8; ++i) {
    int v = loc[i];
    lh[t * 8 + i] = run;
    run += v;
  }
  __syncthreads();
  for (int i = t; i < NBK; i += 256) lcur[i] = lh[i];
  __syncthreads();
  nIt = 0;
  for (int i = base + t; i < end; i += 256) {
    int d = dreg[nIt++];
    int b = d >> BSH;
    int pos = atomicAdd(&lcur[b], 1);
    stage[pos] = ((uint_t)(d & (BNODES - 1)) << 20) | (uint_t)src[i];
  }
  __syncthreads();
  for (int i = t; i < cnt; i += 256) {
    int lo = 0, hi = NBK;
    while (hi - lo > 1) {
      int mid = (lo + hi) >> 1;
      if (lh[mid] <= i) lo = mid; else hi = mid;
    }
    int gb = gmatS[(size_t)lo * B + c];
    parts[gb + (i - lh[lo])] = stage[i];
  }
}

// ---------------- fused: degree + dis + per-bucket CSR (both graphs) ----------

__global__ __launch_bounds__(256) void k_degb2(const uint_t* parts0, const uint_t* parts1,
                                               const int* gmatS0, const int* gmatS1,
                                               int* absRp0, int* absRp1,
                                               int* csrc0, int* csrc1,
                                               float* dis0, float* dis1, int B, int n) {
  const uint_t* parts = blockIdx.y ? parts1 : parts0;
  const int* gmatS = blockIdx.y ? gmatS1 : gmatS0;
  int* absRp = blockIdx.y ? absRp1 : absRp0;
  int* csrc = blockIdx.y ? csrc1 : csrc0;
  float* dis = blockIdx.y ? dis1 : dis0;
  __shared__ int cnt[BNODES];
  __shared__ int lcur[BNODES];
  __shared__ int sEx[BNODES + 1];
  int t = threadIdx.x;
  int b = blockIdx.x;
  if (t < BNODES) cnt[t] = 0;
  __syncthreads();
  int s0 = gmatS[(size_t)b * B];
  int s1 = gmatS[(size_t)(b + 1) * B];
  for (int i = s0 + t; i < s1; i += 256) atomicAdd(&cnt[parts[i] >> 20], 1);
  __syncthreads();
  if (t < BNODES) {            // wave 0: 64-wide scan
    int c = cnt[t];
    int incl = c;
#pragma unroll
    for (int d = 1; d < 64; d <<= 1) {
      int y = __shfl_up(incl, d, 64);
      if (t >= d) incl += y;
    }
    sEx[t] = s0 + incl - c;
    lcur[t] = s0 + incl - c;
    if (t == 63) sEx[64] = s0 + incl;
    int node = (b << BSH) + t;
    if (node < n) dis[node] = rsqrtf((float)(c + 1));
  }
  __syncthreads();
  if (t < BNODES + 1) absRp[(size_t)b * 65 + t] = sEx[t];
  for (int i = s0 + t; i < s1; i += 256) {
    uint_t u = parts[i];
    int dl = u >> 20;
    int pos = atomicAdd(&lcur[dl], 1);
    csrc[pos] = (int)((u & 0xFFFFFu) << 8);   // byte offset of the 256B row
  }
}

// ---------------- fused prep: pack 4 weight matrices + fp32->bf16 x ----------

__global__ void k_prep(const float* W0, const float* W1, const float* W2,
                       const float* W3, ushort_t* P0, ushort_t* P1,
                       ushort_t* P2, ushort_t* P3,
                       const float* __restrict__ x, ushort_t* __restrict__ xb,
                       int total4) {
  int y = blockIdx.y;
  if (y < 4) {
    const float* W = (y == 0) ? W0 : (y == 1) ? W1 : (y == 2) ? W2 : W3;
    ushort_t* P = (y == 0) ? P0 : (y == 1) ? P1 : (y == 2) ? P2 : P3;
    int lim = (y == 3) ? 1024 : 2048;   // enc is K=64 -> KK=2 -> 1024 frags
    int t = blockIdx.x * 256 + threadIdx.x;
    if (t >= lim) return;
    int lane = t & 63;
    int j = (t >> 6) & 7;
    int kk = t >> 9;
    int krow = kk * 32 + (lane >> 4) * 8;
    int col = j * 16 + (lane & 15);
    uint4 v;
    v.x = cvtpk(W[(size_t)(krow + 0) * 128 + col], W[(size_t)(krow + 1) * 128 + col]);
    v.y = cvtpk(W[(size_t)(krow + 2) * 128 + col], W[(size_t)(krow + 3) * 128 + col]);
    v.z = cvtpk(W[(size_t)(krow + 4) * 128 + col], W[(size_t)(krow + 5) * 128 + col]);
    v.w = cvtpk(W[(size_t)(krow + 6) * 128 + col], W[(size_t)(krow + 7) * 128 + col]);
    *(uint4*)&P[(size_t)t * 8] = v;
  } else {
    int i = blockIdx.x * 256 + threadIdx.x;
    if (i < total4) {
      float4 v = *(const float4*)&x[i * 4];
      uint2 p;
      p.x = cvtpk(v.x, v.y);
      p.y = cvtpk(v.z, v.w);
      *(uint2*)&xb[i * 4] = p;
    }
  }
}

// ---------------- fused encoder + layer-0 GEMM ----------------
// Stage 1: enc MFMA (K=64) -> relu(acc+bias) -> bf16 -> LDS tile (padded rows).
// Stage 2: re-read LDS as A-frags, layer-0 MFMA (K=128) -> hb (x dis1), hb2 (x dis2).
// bf16 bits identical to the unfused h0 round-trip -> bit-exact.

__global__ __launch_bounds__(256) void k_enc_l0(const ushort_t* __restrict__ A,
                                                const ushort_t* __restrict__ Wpe,
                                                const float* __restrict__ bias,
                                                const ushort_t* __restrict__ Wp0,
                                                const float* __restrict__ dis1,
                                                const float* __restrict__ dis2,
                                                ushort_t* __restrict__ C1,
                                                ushort_t* __restrict__ C2, int n) {
  __shared__ ushort_t tile[4][16][136];   // +8 ushort pad per row (272B stride)
  int lane = threadIdx.x & 63;
  int wv = threadIdx.x >> 6;
  int r0 = (blockIdx.x * 4 + wv) * 16;
  if (r0 >= n) return;
  int arow = r0 + (lane & 15);
  if (arow >= n) arow = n - 1;
  int colb = lane & 15;

  // ---- stage 1: encoder (K=64) ----
  {
    const ushort_t* aptr = A + (size_t)arow * 64 + (lane >> 4) * 8;
    f32x4 acc[8] = {};
#pragma unroll
    for (int kk = 0; kk < 2; ++kk) {
      short8v a = *(const short8v*)(aptr + kk * 32);
      const ushort_t* wp = Wpe + ((size_t)(kk * 8) * 64 + lane) * 8;
#pragma unroll
      for (int j = 0; j < 8; ++j) {
        short8v b = *(const short8v*)(wp + (size_t)j * 512);
        acc[j] = __builtin_amdgcn_mfma_f32_16x16x32_bf16(a, b, acc[j], 0, 0, 0);
      }
    }
    int rb = (lane >> 4) * 4;
    float bcol[8];
#pragma unroll
    for (int j = 0; j < 8; ++j) bcol[j] = bias[j * 16 + colb];
#pragma unroll
    for (int reg = 0; reg < 4; ++reg) {
#pragma unroll
      for (int j = 0; j < 8; ++j)
        tile[wv][rb + reg][j * 16 + colb] = bf16_1(fmaxf(acc[j][reg] + bcol[j], 0.f));
    }
  }
  __syncthreads();

  // ---- stage 2: layer 0 (K=128) from LDS ----
  {
    const ushort_t* aptr = &tile[wv][lane & 15][(lane >> 4) * 8];
    f32x4 acc[8] = {};
#pragma unroll
    for (int kk = 0; kk < 4; ++kk) {
      short8v a = *(const short8v*)(aptr + kk * 32);
      const ushort_t* wp = Wp0 + ((size_t)(kk * 8) * 64 + lane) * 8;
#pragma unroll
      for (int j = 0; j < 8; ++j) {
        short8v b = *(const short8v*)(wp + (size_t)j * 512);
        acc[j] = __builtin_amdgcn_mfma_f32_16x16x32_bf16(a, b, acc[j], 0, 0, 0);
      }
    }
    int rbase = r0 + (lane >> 4) * 4;
#pragma unroll
    for (int reg = 0; reg < 4; ++reg) {
      int row = rbase + reg;
      if (row < n) {
        float s1 = dis1[row];
        float s2 = dis2[row];
#pragma unroll
        for (int j = 0; j < 8; ++j) {
          float v = acc[j][reg];
          C1[(size_t)row * 128 + j * 16 + colb] = bf16_1(v * s1);
          C2[(size_t)row * 128 + j * 16 + colb] = bf16_1(v * s2);
        }
      }
    }
  }
}

// dual-branch conv GEMM (layers 1,2): blockIdx.y selects branch
__global__ __launch_bounds__(256) void k_gemm_dual(const ushort_t* A0, const ushort_t* A1,
                                                   const ushort_t* __restrict__ Wp,
                                                   const float* dis0, const float* dis1,
                                                   ushort_t* C0, ushort_t* C1, int n) {
  int br = blockIdx.y;
  const ushort_t* A = br ? A1 : A0;
  const float* dis = br ? dis1 : dis0;
  ushort_t* C = br ? C1 : C0;
  int lane = threadIdx.x & 63;
  int wid = threadIdx.x >> 6;
  int r0 = (blockIdx.x * 4 + wid) * 16;
  if (r0 >= n) return;
  int arow = r0 + (lane & 15);
  if (arow >= n) arow = n - 1;
  const ushort_t* aptr = A + (size_t)arow * 128 + (lane >> 4) * 8;

  f32x4 acc[8] = {};
#pragma unroll
  for (int kk = 0; kk < 4; ++kk) {
    short8v a = *(const short8v*)(aptr + kk * 32);
    const ushort_t* wp = Wp + ((size_t)(kk * 8) * 64 + lane) * 8;
#pragma unroll
    for (int j = 0; j < 8; ++j) {
      short8v b = *(const short8v*)(wp + (size_t)j * 512);
      acc[j] = __builtin_amdgcn_mfma_f32_16x16x32_bf16(a, b, acc[j], 0, 0, 0);
    }
  }
  int rbase = r0 + (lane >> 4) * 4;
  int colb = lane & 15;
#pragma unroll
  for (int reg = 0; reg < 4; ++reg) {
    int row = rbase + reg;
    if (row < n) {
      float s = dis[row];
#pragma unroll
      for (int j = 0; j < 8; ++j)
        C[(size_t)row * 128 + j * 16 + colb] = bf16_1(acc[j][reg] * s);
    }
  }
}

// ---------------- dual-branch aggregation + bias + LayerNorm + ReLU ----------------
// Round-13 PASS structure preserved exactly. Self-row + epilogue params issued
// EARLY (loads hoisted; accumulation positions unchanged -> bit-exact).

#define ACC8(U)                                                   \
  a0 += bf_lo(U.x); a1 += bf_hi(U.x); a2 += bf_lo(U.y); a3 += bf_hi(U.y); \
  a4 += bf_lo(U.z); a5 += bf_hi(U.z); a6 += bf_lo(U.w); a7 += bf_hi(U.w);

__global__ __launch_bounds__(256) void k_agg_dual(const char* hwb0, const char* hwb1,
                                                  const int* rpA, const int* rpB,
                                                  const int* csrc0, const int* csrc1,
                                                  const float* dis0, const float* dis1,
                                                  const float* __restrict__ bias,
                                                  const float* __restrict__ g,
                                                  const float* __restrict__ bln,
                                                  uint4* out0, uint4* out1, int n) {
  int br = blockIdx.y;
  const char* hwb = br ? hwb1 : hwb0;
  const int* rp = br ? rpB : rpA;
  const int* csrc = br ? csrc1 : csrc0;
  const float* dis = br ? dis1 : dis0;
  uint4* out4 = br ? out1 : out0;

  __shared__ int sidx[4][64];   // per-wave index staging
  int lane = threadIdx.x & 63;
  int wv = threadIdx.x >> 6;
  int q = lane >> 4;
  int cl = lane & 15;
  int clOff = cl << 4;
  int node = blockIdx.x * 4 + wv;
  if (node >= n) return;
  int ridx = node + (node >> 6);
  int start = rp[ridx];
  int endAbs = rp[ridx + 1];

  // hoisted loads (issued early, consumed after the edge loop)
  uint4 us = *(const uint4*)(hwb + node * 256 + clOff);
  float dn = dis[node];
  float4 b0 = *(const float4*)&bias[cl * 8];
  float4 b1 = *(const float4*)&bias[cl * 8 + 4];
  float4 g0 = *(const float4*)&g[cl * 8];
  float4 g1 = *(const float4*)&g[cl * 8 + 4];
  float4 l0 = *(const float4*)&bln[cl * 8];
  float4 l1 = *(const float4*)&bln[cl * 8 + 4];

  float a0 = 0.f, a1 = 0.f, a2 = 0.f, a3 = 0.f, a4 = 0.f, a5 = 0.f, a6 = 0.f, a7 = 0.f;

  int base = start;
  while (base < endAbs) {
    int take = min(endAbs - base, 64);
    if (lane < take) sidx[wv][lane] = csrc[base + lane];   // one coalesced load
    int e = q;
    for (; e + 12 < take; e += 16) {
      int o0 = sidx[wv][e] + clOff;
      int o1 = sidx[wv][e + 4] + clOff;
      int o2 = sidx[wv][e + 8] + clOff;
      int o3 = sidx[wv][e + 12] + clOff;
      uint4 u = *(const uint4*)(hwb + o0);
      uint4 v = *(const uint4*)(hwb + o1);
      uint4 w = *(const uint4*)(hwb + o2);
      uint4 z = *(const uint4*)(hwb + o3);
      ACC8(u); ACC8(v); ACC8(w); ACC8(z);
    }
    for (; e < take; e += 4) {
      int o0 = sidx[wv][e] + clOff;
      uint4 u = *(const uint4*)(hwb + o0);
      ACC8(u);
    }
    base += take;
  }
  // combine the 4 quarters
#pragma unroll
  for (int m = 16; m < 64; m <<= 1) {
    a0 += __shfl_xor(a0, m, 64); a1 += __shfl_xor(a1, m, 64);
    a2 += __shfl_xor(a2, m, 64); a3 += __shfl_xor(a3, m, 64);
    a4 += __shfl_xor(a4, m, 64); a5 += __shfl_xor(a5, m, 64);
    a6 += __shfl_xor(a6, m, 64); a7 += __shfl_xor(a7, m, 64);
  }
  // self loop (rows pre-scaled by dis[src]); then * dis[node] + bias
  ACC8(us);
  a0 = fmaf(a0, dn, b0.x); a1 = fmaf(a1, dn, b0.y);
  a2 = fmaf(a2, dn, b0.z); a3 = fmaf(a3, dn, b0.w);
  a4 = fmaf(a4, dn, b1.x); a5 = fmaf(a5, dn, b1.y);
  a6 = fmaf(a6, dn, b1.z); a7 = fmaf(a7, dn, b1.w);
  // LayerNorm over 128 channels (reduce within 16-lane quarter)
  float s1v = a0 + a1 + a2 + a3 + a4 + a5 + a6 + a7;
  float s2v = a0 * a0 + a1 * a1 + a2 * a2 + a3 * a3 +
              a4 * a4 + a5 * a5 + a6 * a6 + a7 * a7;
#pragma unroll
  for (int m = 1; m < 16; m <<= 1) {
    s1v += __shfl_xor(s1v, m, 64);
    s2v += __shfl_xor(s2v, m, 64);
  }
  float mean = s1v * (1.0f / 128.0f);
  float var = s2v * (1.0f / 128.0f) - mean * mean;
  float rstd = rsqrtf(var + LN_EPS);
  float y0 = fmaxf(fmaf((a0 - mean) * rstd, g0.x, l0.x), 0.f);
  float y1 = fmaxf(fmaf((a1 - mean) * rstd, g0.y, l0.y), 0.f);
  float y2 = fmaxf(fmaf((a2 - mean) * rstd, g0.z, l0.z), 0.f);
  float y3 = fmaxf(fmaf((a3 - mean) * rstd, g0.w, l0.w), 0.f);
  float y4 = fmaxf(fmaf((a4 - mean) * rstd, g1.x, l1.x), 0.f);
  float y5 = fmaxf(fmaf((a5 - mean) * rstd, g1.y, l1.y), 0.f);
  float y6 = fmaxf(fmaf((a6 - mean) * rstd, g1.z, l1.z), 0.f);
  float y7 = fmaxf(fmaf((a7 - mean) * rstd, g1.w, l1.w), 0.f);
  if (q == 0) {
    uint4 p;
    p.x = cvtpk(y0, y1);
    p.y = cvtpk(y2, y3);
    p.z = cvtpk(y4, y5);
    p.w = cvtpk(y6, y7);
    out4[(size_t)node * 16 + cl] = p;
  }
}

// ---------------- output head ----------------

__global__ __launch_bounds__(256) void k_out(const ushort_t* __restrict__ x1,
                                             const ushort_t* __restrict__ x2,
                                             const float* __restrict__ w,
                                             const float* __restrict__ b,
                                             float* __restrict__ out, int n) {
  __shared__ float wl[256 * 16];
  __shared__ float bl[16];
  int tid = threadIdx.x;
#pragma unroll
  for (int i = 0; i < 4; ++i) {
    int idx = (i * 256 + tid) * 4;
    *(float4*)&wl[idx] = *(const float4*)&w[idx];
  }
  if (tid < 16) bl[tid] = b[tid];
  __syncthreads();
  int node = blockIdx.x * 256 + tid;
  if (node >= n) return;
  float acc[16];
#pragma unroll
  for (int o = 0; o < 16; ++o) acc[o] = bl[o];

  const ushort_t* xr = x1 + (size_t)node * 128;
#pragma unroll 2
  for (int c = 0; c < 128; c += 8) {
    uint4 xv = *(const uint4*)&xr[c];
    float f0 = bf_lo(xv.x), f1 = bf_hi(xv.x), f2 = bf_lo(xv.y), f3 = bf_hi(xv.y);
    float f4 = bf_lo(xv.z), f5 = bf_hi(xv.z), f6 = bf_lo(xv.w), f7 = bf_hi(xv.w);
#pragma unroll
    for (int o = 0; o < 16; ++o) {
      acc[o] = fmaf(f0, wl[(c + 0) * 16 + o],
               fmaf(f1, wl[(c + 1) * 16 + o],
               fmaf(f2, wl[(c + 2) * 16 + o],
               fmaf(f3, wl[(c + 3) * 16 + o],
               fmaf(f4, wl[(c + 4) * 16 + o],
               fmaf(f5, wl[(c + 5) * 16 + o],
               fmaf(f6, wl[(c + 6) * 16 + o],
               fmaf(f7, wl[(c + 7) * 16 + o], acc[o]))))))));
    }
  }
  const ushort_t* xr2 = x2 + (size_t)node * 128;
#pragma unroll 2
  for (int c = 0; c < 128; c += 8) {
    uint4 xv = *(const uint4*)&xr2[c];
    float f0 = bf_lo(xv.x), f1 = bf_hi(xv.x), f2 = bf_lo(xv.y), f3 = bf_hi(xv.y);
    float f4 = bf_lo(xv.z), f5 = bf_hi(xv.z), f6 = bf_lo(xv.w), f7 = bf_hi(xv.w);
#pragma unroll
    for (int o = 0; o < 16; ++o) {
      acc[o] = fmaf(f0, wl[(128 + c + 0) * 16 + o],
               fmaf(f1, wl[(128 + c + 1) * 16 + o],
               fmaf(f2, wl[(128 + c + 2) * 16 + o],
               fmaf(f3, wl[(128 + c + 3) * 16 + o],
               fmaf(f4, wl[(128 + c + 4) * 16 + o],
               fmaf(f5, wl[(128 + c + 5) * 16 + o],
               fmaf(f6, wl[(128 + c + 6) * 16 + o],
               fmaf(f7, wl[(128 + c + 7) * 16 + o], acc[o]))))))));
    }
  }
#pragma unroll
  for (int o = 0; o < 4; ++o) {
    *(float4*)&out[(size_t)node * 16 + o * 4] =
        make_float4(acc[o * 4], acc[o * 4 + 1], acc[o * 4 + 2], acc[o * 4 + 3]);
  }
}

// ---------------- host ----------------

extern "C" void kernel_launch(void* const* d_in, const int* in_sizes, int n_in,
                              void* d_out, int out_size, void* d_ws, size_t ws_size,
                              hipStream_t stream) {
  const float* x = (const float*)d_in[0];
  const int* ei1 = (const int*)d_in[1];
  const int* ei2 = (const int*)d_in[2];
  const float* enc_w = (const float*)d_in[3];
  const float* enc_b = (const float*)d_in[4];
  const float* conv_w[3] = {(const float*)d_in[5], (const float*)d_in[9], (const float*)d_in[13]};
  const float* conv_b[3] = {(const float*)d_in[6], (const float*)d_in[10], (const float*)d_in[14]};
  const float* ln_g[3] = {(const float*)d_in[7], (const float*)d_in[11], (const float*)d_in[15]};
  const float* ln_b[3] = {(const float*)d_in[8], (const float*)d_in[12], (const float*)d_in[16]};
  const float* out_w = (const float*)d_in[17];
  const float* out_b = (const float*)d_in[18];
  float* out = (float*)d_out;

  const int N = NN;
  const int E = in_sizes[1] / 2;
  const int B = (E + EC - 1) / EC;       // partition chunks
  const int M = NBK * B;                 // histogram matrix size

  char* ws = (char*)d_ws;
  size_t off = 0;
  auto alloc = [&](size_t bytes) -> char* {
    char* p = ws + off;
    off += (bytes + 255) & ~(size_t)255;
    return p;
  };
  ushort_t* hb = (ushort_t*)alloc((size_t)N * 128 * 2);
  ushort_t* hb2 = (ushort_t*)alloc((size_t)N * 128 * 2);
  ushort_t* p1 = (ushort_t*)alloc((size_t)N * 128 * 2);
  ushort_t* p2 = (ushort_t*)alloc((size_t)N * 128 * 2);
  ushort_t* xb = (ushort_t*)alloc((size_t)N * 64 * 2);
  ushort_t* wpk[3];
  for (int l = 0; l < 3; ++l) wpk[l] = (ushort_t*)alloc(2048 * 8 * 2);
  ushort_t* wpe = (ushort_t*)alloc(1024 * 8 * 2);

  struct G {
    float* dis; int* absRp; int* gmatC; int* gmatS; int* bsum;
    uint_t* parts; int* csrc; const int* src; const int* dst;
  } g[2];
  for (int i = 0; i < 2; ++i) {
    g[i].dis = (float*)alloc((size_t)N * 4);
    g[i].absRp = (int*)alloc((size_t)NBK * 65 * 4);
    g[i].gmatC = (int*)alloc((size_t)M * 4);
    g[i].gmatS = (int*)alloc((size_t)(M + 1) * 4);
    g[i].bsum = (int*)alloc(64 * 4);
    g[i].parts = (uint_t*)alloc((size_t)E * 4);
    g[i].csrc = (int*)alloc((size_t)(E + 64) * 4);   // +64 pad: 64-wide staging loads
  }
  g[0].src = ei1; g[0].dst = ei1 + E;
  g[1].src = ei2; g[1].dst = ei2 + E;

  int nScanM = (M + 8191) / 8192;

  // CSR build — both graphs per dispatch (gridDim.y = 2)
  k_phist<<<dim3(B, 2), 256, 0, stream>>>(g[0].dst, g[1].dst, g[0].gmatC, g[1].gmatC, E, B);
  k_scanA32<<<dim3(nScanM, 2), 256, 0, stream>>>(g[0].gmatC, g[1].gmatC,
                                                 g[0].gmatS, g[1].gmatS,
                                                 g[0].bsum, g[1].bsum, M);
  k_scanB<<<dim3(1, 2), 64, 0, stream>>>(g[0].bsum, g[1].bsum, nScanM);
  k_scanC32<<<dim3((M + 1 + 255) / 256, 2), 256, 0, stream>>>(g[0].gmatS, g[1].gmatS,
                                                              g[0].bsum, g[1].bsum, M, E);
  k_pscatter<<<dim3(B, 2), 256, 0, stream>>>(g[0].src, g[1].src, g[0].dst, g[1].dst,
                                             g[0].gmatS, g[1].gmatS,
                                             g[0].parts, g[1].parts, E, B);
  k_degb2<<<dim3(NBK, 2), 256, 0, stream>>>(g[0].parts, g[1].parts,
                                            g[0].gmatS, g[1].gmatS,
                                            g[0].absRp, g[1].absRp,
                                            g[0].csrc, g[1].csrc,
                                            g[0].dis, g[1].dis, B, N);

  // weights + input conversion (one fused dispatch)
  int total4 = N * 64 / 4;
  k_prep<<<dim3((total4 + 255) / 256, 5), 256, 0, stream>>>(
      conv_w[0], conv_w[1], conv_w[2], enc_w, wpk[0], wpk[1], wpk[2], wpe,
      x, xb, total4);

  int gb = (N + 63) / 64;
  int ga = (N + 3) / 4;

  // fused encoder + layer-0 GEMM (dual dis outputs; h0 never materialized)
  k_enc_l0<<<gb, 256, 0, stream>>>(xb, wpe, enc_b, wpk[0], g[0].dis, g[1].dis,
                                   hb, hb2, N);
  k_agg_dual<<<dim3(ga, 2), 256, 0, stream>>>((const char*)hb, (const char*)hb2,
                                              g[0].absRp, g[1].absRp,
                                              g[0].csrc, g[1].csrc,
                                              g[0].dis, g[1].dis,
                                              conv_b[0], ln_g[0], ln_b[0],
                                              (uint4*)p1, (uint4*)p2, N);
  // layers 1,2: dual-branch GEMM + dual-branch agg
  for (int l = 1; l < 3; ++l) {
    k_gemm_dual<<<dim3(gb, 2), 256, 0, stream>>>(p1, p2, wpk[l], g[0].dis, g[1].dis,
                                                 hb, hb2, N);
    k_agg_dual<<<dim3(ga, 2), 256, 0, stream>>>((const char*)hb, (const char*)hb2,
                                                g[0].absRp, g[1].absRp,
                                                g[0].csrc, g[1].csrc,
                                                g[0].dis, g[1].dis,
                                                conv_b[l], ln_g[l], ln_b[l],
                                                (uint4*)p1, (uint4*)p2, N);
  }

  k_out<<<(N + 255) / 256, 256, 0, stream>>>(p1, p2, out_w, out_b, out, N);
}

// Round 15
// 575.979 us; speedup vs baseline: 1.1340x; 1.1340x over previous
//
#include <hip/hip_runtime.h>

#define NN 100000
#define LN_EPS 1e-5f
#define BSH 6                       // 64 nodes per bucket
#define BNODES 64
#define NBK ((NN + 63) >> 6)        // 1563 buckets
#define EC 6144                     // edges per partition chunk

typedef unsigned int uint_t;
typedef unsigned short ushort_t;
typedef __attribute__((ext_vector_type(8))) short short8v;
typedef __attribute__((ext_vector_type(4))) float f32x4;

// ---- bf16 helpers ----
// Manual RNE pack ONLY (HW cvt_pk rounds differently: r8; dot2 truncates: r9).
// k_agg loop SHAPE is load-bearing (r12) and its loads must NOT be hoisted
// (r14: +16 VGPR -> occupancy 79%->49%, +30us/dispatch). Keep r13 body verbatim.

__device__ __forceinline__ uint_t cvtpk(float a, float b) {
  uint_t ua = __float_as_uint(a);
  ua = (ua + 0x7FFFu + ((ua >> 16) & 1u)) >> 16;
  uint_t ub = __float_as_uint(b);
  ub = (ub + 0x7FFFu + ((ub >> 16) & 1u)) & 0xFFFF0000u;
  return ua | ub;
}
__device__ __forceinline__ ushort_t bf16_1(float x) {
  uint_t u = __float_as_uint(x);
  return (ushort_t)((u + 0x7FFFu + ((u >> 16) & 1u)) >> 16);
}
__device__ __forceinline__ float bf_lo(uint_t u) { return __uint_as_float(u << 16); }
__device__ __forceinline__ float bf_hi(uint_t u) { return __uint_as_float(u & 0xFFFF0000u); }

// ---------------- scan over gmat matrices (both graphs via blockIdx.y) ------

__global__ __launch_bounds__(256) void k_scanA32(const int* in0, const int* in1,
                                                 int* out0, int* out1,
                                                 int* bsum0, int* bsum1, int n) {
  const int* in = blockIdx.y ? in1 : in0;
  int* out = blockIdx.y ? out1 : out0;
  int* bsum = blockIdx.y ? bsum1 : bsum0;
  __shared__ int sh[256];
  int t = threadIdx.x;
  int base = blockIdx.x * 8192 + t * 32;
  int v[32];
  int s = 0;
#pragma unroll
  for (int i = 0; i < 32; ++i) {
    int idx = base + i;
    v[i] = (idx < n) ? in[idx] : 0;
    s += v[i];
  }
  sh[t] = s;
  __syncthreads();
  for (int d = 1; d < 256; d <<= 1) {
    int a = (t >= d) ? sh[t - d] : 0;
    __syncthreads();
    sh[t] += a;
    __syncthreads();
  }
  int run = sh[t] - s;
  if (t == 255) bsum[blockIdx.x] = sh[255];
#pragma unroll
  for (int i = 0; i < 32; ++i) {
    int idx = base + i;
    if (idx < n) out[idx] = run;
    run += v[i];
  }
}

__global__ void k_scanB(int* bsum0, int* bsum1, int nb) {
  int* bsum = blockIdx.y ? bsum1 : bsum0;
  int t = threadIdx.x;
  int x = (t < nb) ? bsum[t] : 0;
  int incl = x;
#pragma unroll
  for (int d = 1; d < 64; d <<= 1) {
    int y = __shfl_up(incl, d, 64);
    if (t >= d) incl += y;
  }
  if (t < nb) bsum[t] = incl - x;
}

__global__ void k_scanC32(int* rp0, int* rp1, const int* bsum0, const int* bsum1,
                          int n, int total) {
  int* rp = blockIdx.y ? rp1 : rp0;
  const int* bsum = blockIdx.y ? bsum1 : bsum0;
  int i = blockIdx.x * 256 + threadIdx.x;
  if (i < n) rp[i] += bsum[i >> 13];
  else if (i == n) rp[n] = total;
}

// ---------------- partition: per-chunk histogram over buckets (both graphs) --

__global__ __launch_bounds__(256) void k_phist(const int* dst0, const int* dst1,
                                               int* gmatC0, int* gmatC1, int E, int B) {
  const int* dst = blockIdx.y ? dst1 : dst0;
  int* gmatC = blockIdx.y ? gmatC1 : gmatC0;
  __shared__ int lh[NBK];
  int t = threadIdx.x;
  for (int i = t; i < NBK; i += 256) lh[i] = 0;
  __syncthreads();
  int base = blockIdx.x * EC;
  int end = min(E, base + EC);
  for (int i = base + t; i < end; i += 256) atomicAdd(&lh[dst[i] >> BSH], 1);
  __syncthreads();
  for (int b = t; b < NBK; b += 256) gmatC[(size_t)b * B + blockIdx.x] = lh[b];
}

// LDS counting sort of one chunk; flat copy-out via binary search (both graphs).
// dst chunk register-cached (read global once). parts[pos] = (dst&63)<<20 | src
__global__ __launch_bounds__(256) void k_pscatter(const int* src0, const int* src1,
                                                  const int* dst0, const int* dst1,
                                                  const int* gmatS0, const int* gmatS1,
                                                  uint_t* parts0, uint_t* parts1,
                                                  int E, int B) {
  const int* src = blockIdx.y ? src1 : src0;
  const int* dst = blockIdx.y ? dst1 : dst0;
  const int* gmatS = blockIdx.y ? gmatS1 : gmatS0;
  uint_t* parts = blockIdx.y ? parts1 : parts0;
  __shared__ uint_t stage[EC];   // 24 KB
  __shared__ int lh[2048];
  __shared__ int lcur[NBK];
  __shared__ int sh[256];
  int t = threadIdx.x;
  int c = blockIdx.x;
  for (int i = t; i < 2048; i += 256) lh[i] = 0;
  __syncthreads();
  int base = c * EC;
  int end = min(E, base + EC);
  int cnt = end - base;
  int dreg[EC / 256];           // 24 dst values per thread
  int nIt = 0;
  for (int i = base + t; i < end; i += 256) {
    int d = dst[i];
    dreg[nIt++] = d;
    atomicAdd(&lh[d >> BSH], 1);
  }
  __syncthreads();
  int loc[8];
  int s = 0;
#pragma unroll
  for (int i = 0; i < 8; ++i) {
    loc[i] = lh[t * 8 + i];
    s += loc[i];
  }
  sh[t] = s;
  __syncthreads();
  for (int d = 1; d < 256; d <<= 1) {
    int a = (t >= d) ? sh[t - d] : 0;
    __syncthreads();
    sh[t] += a;
    __syncthreads();
  }
  int run = sh[t] - s;
#pragma unroll
  for (int i = 0; i < 8; ++i) {
    int v = loc[i];
    lh[t * 8 + i] = run;
    run += v;
  }
  __syncthreads();
  for (int i = t; i < NBK; i += 256) lcur[i] = lh[i];
  __syncthreads();
  nIt = 0;
  for (int i = base + t; i < end; i += 256) {
    int d = dreg[nIt++];
    int b = d >> BSH;
    int pos = atomicAdd(&lcur[b], 1);
    stage[pos] = ((uint_t)(d & (BNODES - 1)) << 20) | (uint_t)src[i];
  }
  __syncthreads();
  for (int i = t; i < cnt; i += 256) {
    int lo = 0, hi = NBK;
    while (hi - lo > 1) {
      int mid = (lo + hi) >> 1;
      if (lh[mid] <= i) lo = mid; else hi = mid;
    }
    int gb = gmatS[(size_t)lo * B + c];
    parts[gb + (i - lh[lo])] = stage[i];
  }
}

// ---------------- fused: degree + dis + per-bucket CSR (both graphs) ----------

__global__ __launch_bounds__(256) void k_degb2(const uint_t* parts0, const uint_t* parts1,
                                               const int* gmatS0, const int* gmatS1,
                                               int* absRp0, int* absRp1,
                                               int* csrc0, int* csrc1,
                                               float* dis0, float* dis1, int B, int n) {
  const uint_t* parts = blockIdx.y ? parts1 : parts0;
  const int* gmatS = blockIdx.y ? gmatS1 : gmatS0;
  int* absRp = blockIdx.y ? absRp1 : absRp0;
  int* csrc = blockIdx.y ? csrc1 : csrc0;
  float* dis = blockIdx.y ? dis1 : dis0;
  __shared__ int cnt[BNODES];
  __shared__ int lcur[BNODES];
  __shared__ int sEx[BNODES + 1];
  int t = threadIdx.x;
  int b = blockIdx.x;
  if (t < BNODES) cnt[t] = 0;
  __syncthreads();
  int s0 = gmatS[(size_t)b * B];
  int s1 = gmatS[(size_t)(b + 1) * B];
  for (int i = s0 + t; i < s1; i += 256) atomicAdd(&cnt[parts[i] >> 20], 1);
  __syncthreads();
  if (t < BNODES) {            // wave 0: 64-wide scan
    int c = cnt[t];
    int incl = c;
#pragma unroll
    for (int d = 1; d < 64; d <<= 1) {
      int y = __shfl_up(incl, d, 64);
      if (t >= d) incl += y;
    }
    sEx[t] = s0 + incl - c;
    lcur[t] = s0 + incl - c;
    if (t == 63) sEx[64] = s0 + incl;
    int node = (b << BSH) + t;
    if (node < n) dis[node] = rsqrtf((float)(c + 1));
  }
  __syncthreads();
  if (t < BNODES + 1) absRp[(size_t)b * 65 + t] = sEx[t];
  for (int i = s0 + t; i < s1; i += 256) {
    uint_t u = parts[i];
    int dl = u >> 20;
    int pos = atomicAdd(&lcur[dl], 1);
    csrc[pos] = (int)((u & 0xFFFFFu) << 8);   // byte offset of the 256B row
  }
}

// ---------------- fused prep: pack 4 weight matrices + fp32->bf16 x ----------

__global__ void k_prep(const float* W0, const float* W1, const float* W2,
                       const float* W3, ushort_t* P0, ushort_t* P1,
                       ushort_t* P2, ushort_t* P3,
                       const float* __restrict__ x, ushort_t* __restrict__ xb,
                       int total4) {
  int y = blockIdx.y;
  if (y < 4) {
    const float* W = (y == 0) ? W0 : (y == 1) ? W1 : (y == 2) ? W2 : W3;
    ushort_t* P = (y == 0) ? P0 : (y == 1) ? P1 : (y == 2) ? P2 : P3;
    int lim = (y == 3) ? 1024 : 2048;   // enc is K=64 -> KK=2 -> 1024 frags
    int t = blockIdx.x * 256 + threadIdx.x;
    if (t >= lim) return;
    int lane = t & 63;
    int j = (t >> 6) & 7;
    int kk = t >> 9;
    int krow = kk * 32 + (lane >> 4) * 8;
    int col = j * 16 + (lane & 15);
    uint4 v;
    v.x = cvtpk(W[(size_t)(krow + 0) * 128 + col], W[(size_t)(krow + 1) * 128 + col]);
    v.y = cvtpk(W[(size_t)(krow + 2) * 128 + col], W[(size_t)(krow + 3) * 128 + col]);
    v.z = cvtpk(W[(size_t)(krow + 4) * 128 + col], W[(size_t)(krow + 5) * 128 + col]);
    v.w = cvtpk(W[(size_t)(krow + 6) * 128 + col], W[(size_t)(krow + 7) * 128 + col]);
    *(uint4*)&P[(size_t)t * 8] = v;
  } else {
    int i = blockIdx.x * 256 + threadIdx.x;
    if (i < total4) {
      float4 v = *(const float4*)&x[i * 4];
      uint2 p;
      p.x = cvtpk(v.x, v.y);
      p.y = cvtpk(v.z, v.w);
      *(uint2*)&xb[i * 4] = p;
    }
  }
}

// ---------------- fused encoder + layer-0 GEMM ----------------
// Stage 1: enc MFMA (K=64) -> relu(acc+bias) -> bf16 -> LDS tile (padded rows).
// Stage 2: re-read LDS as A-frags, layer-0 MFMA (K=128) -> hb (x dis1), hb2 (x dis2).
// bf16 bits identical to the unfused h0 round-trip -> bit-exact.

__global__ __launch_bounds__(256) void k_enc_l0(const ushort_t* __restrict__ A,
                                                const ushort_t* __restrict__ Wpe,
                                                const float* __restrict__ bias,
                                                const ushort_t* __restrict__ Wp0,
                                                const float* __restrict__ dis1,
                                                const float* __restrict__ dis2,
                                                ushort_t* __restrict__ C1,
                                                ushort_t* __restrict__ C2, int n) {
  __shared__ ushort_t tile[4][16][136];   // +8 ushort pad per row (272B stride)
  int lane = threadIdx.x & 63;
  int wv = threadIdx.x >> 6;
  int r0 = (blockIdx.x * 4 + wv) * 16;
  if (r0 >= n) return;
  int arow = r0 + (lane & 15);
  if (arow >= n) arow = n - 1;
  int colb = lane & 15;

  // ---- stage 1: encoder (K=64) ----
  {
    const ushort_t* aptr = A + (size_t)arow * 64 + (lane >> 4) * 8;
    f32x4 acc[8] = {};
#pragma unroll
    for (int kk = 0; kk < 2; ++kk) {
      short8v a = *(const short8v*)(aptr + kk * 32);
      const ushort_t* wp = Wpe + ((size_t)(kk * 8) * 64 + lane) * 8;
#pragma unroll
      for (int j = 0; j < 8; ++j) {
        short8v b = *(const short8v*)(wp + (size_t)j * 512);
        acc[j] = __builtin_amdgcn_mfma_f32_16x16x32_bf16(a, b, acc[j], 0, 0, 0);
      }
    }
    int rb = (lane >> 4) * 4;
    float bcol[8];
#pragma unroll
    for (int j = 0; j < 8; ++j) bcol[j] = bias[j * 16 + colb];
#pragma unroll
    for (int reg = 0; reg < 4; ++reg) {
#pragma unroll
      for (int j = 0; j < 8; ++j)
        tile[wv][rb + reg][j * 16 + colb] = bf16_1(fmaxf(acc[j][reg] + bcol[j], 0.f));
    }
  }
  __syncthreads();

  // ---- stage 2: layer 0 (K=128) from LDS ----
  {
    const ushort_t* aptr = &tile[wv][lane & 15][(lane >> 4) * 8];
    f32x4 acc[8] = {};
#pragma unroll
    for (int kk = 0; kk < 4; ++kk) {
      short8v a = *(const short8v*)(aptr + kk * 32);
      const ushort_t* wp = Wp0 + ((size_t)(kk * 8) * 64 + lane) * 8;
#pragma unroll
      for (int j = 0; j < 8; ++j) {
        short8v b = *(const short8v*)(wp + (size_t)j * 512);
        acc[j] = __builtin_amdgcn_mfma_f32_16x16x32_bf16(a, b, acc[j], 0, 0, 0);
      }
    }
    int rbase = r0 + (lane >> 4) * 4;
#pragma unroll
    for (int reg = 0; reg < 4; ++reg) {
      int row = rbase + reg;
      if (row < n) {
        float s1 = dis1[row];
        float s2 = dis2[row];
#pragma unroll
        for (int j = 0; j < 8; ++j) {
          float v = acc[j][reg];
          C1[(size_t)row * 128 + j * 16 + colb] = bf16_1(v * s1);
          C2[(size_t)row * 128 + j * 16 + colb] = bf16_1(v * s2);
        }
      }
    }
  }
}

// dual-branch conv GEMM (layers 1,2): blockIdx.y selects branch
__global__ __launch_bounds__(256) void k_gemm_dual(const ushort_t* A0, const ushort_t* A1,
                                                   const ushort_t* __restrict__ Wp,
                                                   const float* dis0, const float* dis1,
                                                   ushort_t* C0, ushort_t* C1, int n) {
  int br = blockIdx.y;
  const ushort_t* A = br ? A1 : A0;
  const float* dis = br ? dis1 : dis0;
  ushort_t* C = br ? C1 : C0;
  int lane = threadIdx.x & 63;
  int wid = threadIdx.x >> 6;
  int r0 = (blockIdx.x * 4 + wid) * 16;
  if (r0 >= n) return;
  int arow = r0 + (lane & 15);
  if (arow >= n) arow = n - 1;
  const ushort_t* aptr = A + (size_t)arow * 128 + (lane >> 4) * 8;

  f32x4 acc[8] = {};
#pragma unroll
  for (int kk = 0; kk < 4; ++kk) {
    short8v a = *(const short8v*)(aptr + kk * 32);
    const ushort_t* wp = Wp + ((size_t)(kk * 8) * 64 + lane) * 8;
#pragma unroll
    for (int j = 0; j < 8; ++j) {
      short8v b = *(const short8v*)(wp + (size_t)j * 512);
      acc[j] = __builtin_amdgcn_mfma_f32_16x16x32_bf16(a, b, acc[j], 0, 0, 0);
    }
  }
  int rbase = r0 + (lane >> 4) * 4;
  int colb = lane & 15;
#pragma unroll
  for (int reg = 0; reg < 4; ++reg) {
    int row = rbase + reg;
    if (row < n) {
      float s = dis[row];
#pragma unroll
      for (int j = 0; j < 8; ++j)
        C[(size_t)row * 128 + j * 16 + colb] = bf16_1(acc[j][reg] * s);
    }
  }
}

// ---------------- dual-branch aggregation + bias + LayerNorm + ReLU ----------------
// Round-13 PASS body VERBATIM (28 VGPR, ~79% occupancy). Loads NOT hoisted (r14).

#define ACC8(U)                                                   \
  a0 += bf_lo(U.x); a1 += bf_hi(U.x); a2 += bf_lo(U.y); a3 += bf_hi(U.y); \
  a4 += bf_lo(U.z); a5 += bf_hi(U.z); a6 += bf_lo(U.w); a7 += bf_hi(U.w);

__global__ __launch_bounds__(256) void k_agg_dual(const char* hwb0, const char* hwb1,
                                                  const int* rpA, const int* rpB,
                                                  const int* csrc0, const int* csrc1,
                                                  const float* dis0, const float* dis1,
                                                  const float* __restrict__ bias,
                                                  const float* __restrict__ g,
                                                  const float* __restrict__ bln,
                                                  uint4* out0, uint4* out1, int n) {
  int br = blockIdx.y;
  const char* hwb = br ? hwb1 : hwb0;
  const int* rp = br ? rpB : rpA;
  const int* csrc = br ? csrc1 : csrc0;
  const float* dis = br ? dis1 : dis0;
  uint4* out4 = br ? out1 : out0;

  __shared__ int sidx[4][64];   // per-wave index staging (no cross-wave sharing)
  int lane = threadIdx.x & 63;
  int wv = threadIdx.x >> 6;
  int q = lane >> 4;
  int cl = lane & 15;
  int clOff = cl << 4;
  int node = blockIdx.x * 4 + wv;
  if (node >= n) return;
  int ridx = node + (node >> 6);
  int start = rp[ridx];
  int endAbs = rp[ridx + 1];
  float a0 = 0.f, a1 = 0.f, a2 = 0.f, a3 = 0.f, a4 = 0.f, a5 = 0.f, a6 = 0.f, a7 = 0.f;

  int base = start;
  while (base < endAbs) {
    int take = min(endAbs - base, 64);
    if (lane < take) sidx[wv][lane] = csrc[base + lane];   // one coalesced load
    int e = q;
    for (; e + 12 < take; e += 16) {
      int o0 = sidx[wv][e] + clOff;
      int o1 = sidx[wv][e + 4] + clOff;
      int o2 = sidx[wv][e + 8] + clOff;
      int o3 = sidx[wv][e + 12] + clOff;
      uint4 u = *(const uint4*)(hwb + o0);
      uint4 v = *(const uint4*)(hwb + o1);
      uint4 w = *(const uint4*)(hwb + o2);
      uint4 z = *(const uint4*)(hwb + o3);
      ACC8(u); ACC8(v); ACC8(w); ACC8(z);
    }
    for (; e < take; e += 4) {
      int o0 = sidx[wv][e] + clOff;
      uint4 u = *(const uint4*)(hwb + o0);
      ACC8(u);
    }
    base += take;
  }
  // combine the 4 quarters
#pragma unroll
  for (int m = 16; m < 64; m <<= 1) {
    a0 += __shfl_xor(a0, m, 64); a1 += __shfl_xor(a1, m, 64);
    a2 += __shfl_xor(a2, m, 64); a3 += __shfl_xor(a3, m, 64);
    a4 += __shfl_xor(a4, m, 64); a5 += __shfl_xor(a5, m, 64);
    a6 += __shfl_xor(a6, m, 64); a7 += __shfl_xor(a7, m, 64);
  }
  // self loop (rows pre-scaled by dis[src]); then * dis[node] + bias
  uint4 us = *(const uint4*)(hwb + node * 256 + clOff);
  ACC8(us);
  float dn = dis[node];
  float4 b0 = *(const float4*)&bias[cl * 8];
  float4 b1 = *(const float4*)&bias[cl * 8 + 4];
  a0 = fmaf(a0, dn, b0.x); a1 = fmaf(a1, dn, b0.y);
  a2 = fmaf(a2, dn, b0.z); a3 = fmaf(a3, dn, b0.w);
  a4 = fmaf(a4, dn, b1.x); a5 = fmaf(a5, dn, b1.y);
  a6 = fmaf(a6, dn, b1.z); a7 = fmaf(a7, dn, b1.w);
  // LayerNorm over 128 channels (reduce within 16-lane quarter)
  float s1v = a0 + a1 + a2 + a3 + a4 + a5 + a6 + a7;
  float s2v = a0 * a0 + a1 * a1 + a2 * a2 + a3 * a3 +
              a4 * a4 + a5 * a5 + a6 * a6 + a7 * a7;
#pragma unroll
  for (int m = 1; m < 16; m <<= 1) {
    s1v += __shfl_xor(s1v, m, 64);
    s2v += __shfl_xor(s2v, m, 64);
  }
  float mean = s1v * (1.0f / 128.0f);
  float var = s2v * (1.0f / 128.0f) - mean * mean;
  float rstd = rsqrtf(var + LN_EPS);
  float4 g0 = *(const float4*)&g[cl * 8];
  float4 g1 = *(const float4*)&g[cl * 8 + 4];
  float4 l0 = *(const float4*)&bln[cl * 8];
  float4 l1 = *(const float4*)&bln[cl * 8 + 4];
  float y0 = fmaxf(fmaf((a0 - mean) * rstd, g0.x, l0.x), 0.f);
  float y1 = fmaxf(fmaf((a1 - mean) * rstd, g0.y, l0.y), 0.f);
  float y2 = fmaxf(fmaf((a2 - mean) * rstd, g0.z, l0.z), 0.f);
  float y3 = fmaxf(fmaf((a3 - mean) * rstd, g0.w, l0.w), 0.f);
  float y4 = fmaxf(fmaf((a4 - mean) * rstd, g1.x, l1.x), 0.f);
  float y5 = fmaxf(fmaf((a5 - mean) * rstd, g1.y, l1.y), 0.f);
  float y6 = fmaxf(fmaf((a6 - mean) * rstd, g1.z, l1.z), 0.f);
  float y7 = fmaxf(fmaf((a7 - mean) * rstd, g1.w, l1.w), 0.f);
  if (q == 0) {
    uint4 p;
    p.x = cvtpk(y0, y1);
    p.y = cvtpk(y2, y3);
    p.z = cvtpk(y4, y5);
    p.w = cvtpk(y6, y7);
    out4[(size_t)node * 16 + cl] = p;
  }
}

// ---------------- output head ----------------

__global__ __launch_bounds__(256) void k_out(const ushort_t* __restrict__ x1,
                                             const ushort_t* __restrict__ x2,
                                             const float* __restrict__ w,
                                             const float* __restrict__ b,
                                             float* __restrict__ out, int n) {
  __shared__ float wl[256 * 16];
  __shared__ float bl[16];
  int tid = threadIdx.x;
#pragma unroll
  for (int i = 0; i < 4; ++i) {
    int idx = (i * 256 + tid) * 4;
    *(float4*)&wl[idx] = *(const float4*)&w[idx];
  }
  if (tid < 16) bl[tid] = b[tid];
  __syncthreads();
  int node = blockIdx.x * 256 + tid;
  if (node >= n) return;
  float acc[16];
#pragma unroll
  for (int o = 0; o < 16; ++o) acc[o] = bl[o];

  const ushort_t* xr = x1 + (size_t)node * 128;
#pragma unroll 2
  for (int c = 0; c < 128; c += 8) {
    uint4 xv = *(const uint4*)&xr[c];
    float f0 = bf_lo(xv.x), f1 = bf_hi(xv.x), f2 = bf_lo(xv.y), f3 = bf_hi(xv.y);
    float f4 = bf_lo(xv.z), f5 = bf_hi(xv.z), f6 = bf_lo(xv.w), f7 = bf_hi(xv.w);
#pragma unroll
    for (int o = 0; o < 16; ++o) {
      acc[o] = fmaf(f0, wl[(c + 0) * 16 + o],
               fmaf(f1, wl[(c + 1) * 16 + o],
               fmaf(f2, wl[(c + 2) * 16 + o],
               fmaf(f3, wl[(c + 3) * 16 + o],
               fmaf(f4, wl[(c + 4) * 16 + o],
               fmaf(f5, wl[(c + 5) * 16 + o],
               fmaf(f6, wl[(c + 6) * 16 + o],
               fmaf(f7, wl[(c + 7) * 16 + o], acc[o]))))))));
    }
  }
  const ushort_t* xr2 = x2 + (size_t)node * 128;
#pragma unroll 2
  for (int c = 0; c < 128; c += 8) {
    uint4 xv = *(const uint4*)&xr2[c];
    float f0 = bf_lo(xv.x), f1 = bf_hi(xv.x), f2 = bf_lo(xv.y), f3 = bf_hi(xv.y);
    float f4 = bf_lo(xv.z), f5 = bf_hi(xv.z), f6 = bf_lo(xv.w), f7 = bf_hi(xv.w);
#pragma unroll
    for (int o = 0; o < 16; ++o) {
      acc[o] = fmaf(f0, wl[(128 + c + 0) * 16 + o],
               fmaf(f1, wl[(128 + c + 1) * 16 + o],
               fmaf(f2, wl[(128 + c + 2) * 16 + o],
               fmaf(f3, wl[(128 + c + 3) * 16 + o],
               fmaf(f4, wl[(128 + c + 4) * 16 + o],
               fmaf(f5, wl[(128 + c + 5) * 16 + o],
               fmaf(f6, wl[(128 + c + 6) * 16 + o],
               fmaf(f7, wl[(128 + c + 7) * 16 + o], acc[o]))))))));
    }
  }
#pragma unroll
  for (int o = 0; o < 4; ++o) {
    *(float4*)&out[(size_t)node * 16 + o * 4] =
        make_float4(acc[o * 4], acc[o * 4 + 1], acc[o * 4 + 2], acc[o * 4 + 3]);
  }
}

// ---------------- host ----------------

extern "C" void kernel_launch(void* const* d_in, const int* in_sizes, int n_in,
                              void* d_out, int out_size, void* d_ws, size_t ws_size,
                              hipStream_t stream) {
  const float* x = (const float*)d_in[0];
  const int* ei1 = (const int*)d_in[1];
  const int* ei2 = (const int*)d_in[2];
  const float* enc_w = (const float*)d_in[3];
  const float* enc_b = (const float*)d_in[4];
  const float* conv_w[3] = {(const float*)d_in[5], (const float*)d_in[9], (const float*)d_in[13]};
  const float* conv_b[3] = {(const float*)d_in[6], (const float*)d_in[10], (const float*)d_in[14]};
  const float* ln_g[3] = {(const float*)d_in[7], (const float*)d_in[11], (const float*)d_in[15]};
  const float* ln_b[3] = {(const float*)d_in[8], (const float*)d_in[12], (const float*)d_in[16]};
  const float* out_w = (const float*)d_in[17];
  const float* out_b = (const float*)d_in[18];
  float* out = (float*)d_out;

  const int N = NN;
  const int E = in_sizes[1] / 2;
  const int B = (E + EC - 1) / EC;       // partition chunks
  const int M = NBK * B;                 // histogram matrix size

  char* ws = (char*)d_ws;
  size_t off = 0;
  auto alloc = [&](size_t bytes) -> char* {
    char* p = ws + off;
    off += (bytes + 255) & ~(size_t)255;
    return p;
  };
  ushort_t* hb = (ushort_t*)alloc((size_t)N * 128 * 2);
  ushort_t* hb2 = (ushort_t*)alloc((size_t)N * 128 * 2);
  ushort_t* p1 = (ushort_t*)alloc((size_t)N * 128 * 2);
  ushort_t* p2 = (ushort_t*)alloc((size_t)N * 128 * 2);
  ushort_t* xb = (ushort_t*)alloc((size_t)N * 64 * 2);
  ushort_t* wpk[3];
  for (int l = 0; l < 3; ++l) wpk[l] = (ushort_t*)alloc(2048 * 8 * 2);
  ushort_t* wpe = (ushort_t*)alloc(1024 * 8 * 2);

  struct G {
    float* dis; int* absRp; int* gmatC; int* gmatS; int* bsum;
    uint_t* parts; int* csrc; const int* src; const int* dst;
  } g[2];
  for (int i = 0; i < 2; ++i) {
    g[i].dis = (float*)alloc((size_t)N * 4);
    g[i].absRp = (int*)alloc((size_t)NBK * 65 * 4);
    g[i].gmatC = (int*)alloc((size_t)M * 4);
    g[i].gmatS = (int*)alloc((size_t)(M + 1) * 4);
    g[i].bsum = (int*)alloc(64 * 4);
    g[i].parts = (uint_t*)alloc((size_t)E * 4);
    g[i].csrc = (int*)alloc((size_t)(E + 64) * 4);   // +64 pad: 64-wide staging loads
  }
  g[0].src = ei1; g[0].dst = ei1 + E;
  g[1].src = ei2; g[1].dst = ei2 + E;

  int nScanM = (M + 8191) / 8192;

  // CSR build — both graphs per dispatch (gridDim.y = 2)
  k_phist<<<dim3(B, 2), 256, 0, stream>>>(g[0].dst, g[1].dst, g[0].gmatC, g[1].gmatC, E, B);
  k_scanA32<<<dim3(nScanM, 2), 256, 0, stream>>>(g[0].gmatC, g[1].gmatC,
                                                 g[0].gmatS, g[1].gmatS,
                                                 g[0].bsum, g[1].bsum, M);
  k_scanB<<<dim3(1, 2), 64, 0, stream>>>(g[0].bsum, g[1].bsum, nScanM);
  k_scanC32<<<dim3((M + 1 + 255) / 256, 2), 256, 0, stream>>>(g[0].gmatS, g[1].gmatS,
                                                              g[0].bsum, g[1].bsum, M, E);
  k_pscatter<<<dim3(B, 2), 256, 0, stream>>>(g[0].src, g[1].src, g[0].dst, g[1].dst,
                                             g[0].gmatS, g[1].gmatS,
                                             g[0].parts, g[1].parts, E, B);
  k_degb2<<<dim3(NBK, 2), 256, 0, stream>>>(g[0].parts, g[1].parts,
                                            g[0].gmatS, g[1].gmatS,
                                            g[0].absRp, g[1].absRp,
                                            g[0].csrc, g[1].csrc,
                                            g[0].dis, g[1].dis, B, N);

  // weights + input conversion (one fused dispatch)
  int total4 = N * 64 / 4;
  k_prep<<<dim3((total4 + 255) / 256, 5), 256, 0, stream>>>(
      conv_w[0], conv_w[1], conv_w[2], enc_w, wpk[0], wpk[1], wpk[2], wpe,
      x, xb, total4);

  int gb = (N + 63) / 64;
  int ga = (N + 3) / 4;

  // fused encoder + layer-0 GEMM (dual dis outputs; h0 never materialized)
  k_enc_l0<<<gb, 256, 0, stream>>>(xb, wpe, enc_b, wpk[0], g[0].dis, g[1].dis,
                                   hb, hb2, N);
  k_agg_dual<<<dim3(ga, 2), 256, 0, stream>>>((const char*)hb, (const char*)hb2,
                                              g[0].absRp, g[1].absRp,
                                              g[0].csrc, g[1].csrc,
                                              g[0].dis, g[1].dis,
                                              conv_b[0], ln_g[0], ln_b[0],
                                              (uint4*)p1, (uint4*)p2, N);
  // layers 1,2: dual-branch GEMM + dual-branch agg
  for (int l = 1; l < 3; ++l) {
    k_gemm_dual<<<dim3(gb, 2), 256, 0, stream>>>(p1, p2, wpk[l], g[0].dis, g[1].dis,
                                                 hb, hb2, N);
    k_agg_dual<<<dim3(ga, 2), 256, 0, stream>>>((const char*)hb, (const char*)hb2,
                                                g[0].absRp, g[1].absRp,
                                                g[0].csrc, g[1].csrc,
                                                g[0].dis, g[1].dis,
                                                conv_b[l], ln_g[l], ln_b[l],
                                                (uint4*)p1, (uint4*)p2, N);
  }

  k_out<<<(N + 255) / 256, 256, 0, stream>>>(p1, p2, out_w, out_b, out, N);
}